// Round 11
// baseline (414.119 us; speedup 1.0000x reference)
//
#include <hip/hip_runtime.h>

#define F 128
#define NN 100000
#define NB2 ((NN + 1023) / 1024)   // 98 scan blocks
#define HBLK 256                   // hist/scatter block count
#define LD 136                     // padded LDS row stride in bf16 elems
#define N4 (NN * F / 4)            // 3.2M float4's in x

typedef __attribute__((ext_vector_type(8))) short short8;   // 8 bf16 = 16 B
typedef __attribute__((ext_vector_type(4))) float f32x4;
typedef __attribute__((ext_vector_type(2))) float f32x2;
typedef __attribute__((ext_vector_type(4))) int int4v;
typedef __attribute__((ext_vector_type(2))) int int2v;
typedef __attribute__((ext_vector_type(4))) unsigned short us4;
typedef unsigned short ushort_t;
typedef unsigned char uchar_t;

// ---------------------------------------------------------------------------
// bf16 helpers (RNE)
// ---------------------------------------------------------------------------
__device__ __forceinline__ ushort_t f2b(float f) {
    union { float f; unsigned u; } x;
    x.f = f;
    unsigned r = x.u + 0x7fffu + ((x.u >> 16) & 1u);
    return (ushort_t)(r >> 16);
}
__device__ __forceinline__ float b2f(ushort_t u) {
    union { unsigned u; float f; } x;
    x.u = ((unsigned)u) << 16;
    return x.f;
}

// ---------------------------------------------------------------------------
// fp8 e4m3fn (OCP) helpers (r9-proven).
// ---------------------------------------------------------------------------
__device__ __forceinline__ unsigned f_to_e4m3(float v) {
    union { float f; unsigned b; } x; x.f = v;
    unsigned s = (x.b >> 24) & 0x80u;
    float a = fabsf(v);
    if (!(a < 448.f)) return s | 0x7Eu;                       // saturate
    if (a < 0.015625f) return s | (unsigned)__float2int_rn(a * 512.f);  // subnormal
    unsigned ab = x.b & 0x7FFFFFFFu;
    unsigned r = ab + 0x7FFFFu + ((ab >> 20) & 1u);           // RNE at bit 20
    unsigned e = (r >> 23) - 120u;                            // rebias 127->7
    return s | ((e << 3) | ((r >> 20) & 7u));
}
__device__ __forceinline__ float e4m3_to_f(unsigned u) {
    unsigned s = (u & 0x80u) << 24;
    unsigned e = (u >> 3) & 15u;
    unsigned m = u & 7u;
    union { unsigned b; float f; } x;
    x.b = s | ((e + 120u) << 23) | (m << 20);
    float f = x.f;
    if (e == 0) f = fmaf(f, 2.f, s ? 0.015625f : -0.015625f);  // subnormal fix
    return f;
}
__device__ __forceinline__ unsigned pack4_fp8(float f0, float f1, float f2, float f3) {
#if __has_builtin(__builtin_amdgcn_cvt_pk_fp8_f32)
    int w = 0;
    w = __builtin_amdgcn_cvt_pk_fp8_f32(f0, f1, w, false);
    w = __builtin_amdgcn_cvt_pk_fp8_f32(f2, f3, w, true);
    return (unsigned)w;
#else
    return f_to_e4m3(f0) | (f_to_e4m3(f1) << 8) | (f_to_e4m3(f2) << 16) |
           (f_to_e4m3(f3) << 24);
#endif
}
__device__ __forceinline__ void dec4(int w, float* o) {  // 4 fp8 bytes -> f32
#if __has_builtin(__builtin_amdgcn_cvt_pk_f32_fp8)
    f32x2 a = __builtin_amdgcn_cvt_pk_f32_fp8(w, false);
    f32x2 b = __builtin_amdgcn_cvt_pk_f32_fp8(w, true);
    o[0] = a[0]; o[1] = a[1]; o[2] = b[0]; o[3] = b[1];
#else
    o[0] = e4m3_to_f((unsigned)w & 0xFFu);
    o[1] = e4m3_to_f(((unsigned)w >> 8) & 0xFFu);
    o[2] = e4m3_to_f(((unsigned)w >> 16) & 0xFFu);
    o[3] = e4m3_to_f(((unsigned)w >> 24) & 0xFFu);
#endif
}

// Inline-asm loads (r8-proven): distinct "=v" outputs keep all batch results
// live -> true MLP. Use only after the vmcnt(0) + register-redefine fence.
__device__ __forceinline__ int4v ld_row16(const ushort_t* p) {
    int4v r;
    asm volatile("global_load_dwordx4 %0, %1, off" : "=v"(r) : "v"(p) : "memory");
    return r;
}
__device__ __forceinline__ int2v ld_row8(const uchar_t* p) {
    int2v r;
    asm volatile("global_load_dwordx2 %0, %1, off" : "=v"(r) : "v"(p) : "memory");
    return r;
}

// ---------------------------------------------------------------------------
// K1 (fused): [0,HBLK): per-dst degree hist via global atomics (100k
//   counters, ~16 adds each -> negligible contention; replaces the per-chunk
//   H matrix + column scan of the old sort chain).
//   [HBLK,HBLK+64): W -> WT bf16 transpose. Rest: x -> bf16 + fp8 cvt.
// ---------------------------------------------------------------------------
__global__ __launch_bounds__(256) void k1_fused(
    const int* __restrict__ dst, int* __restrict__ deg, int E,
    const float* __restrict__ Wa, const float* __restrict__ Wb,
    const float* __restrict__ Wc, const float* __restrict__ Wd,
    ushort_t* __restrict__ Oa, ushort_t* __restrict__ Ob,
    ushort_t* __restrict__ Oc, ushort_t* __restrict__ Od,
    const float* __restrict__ X, ushort_t* __restrict__ Y,
    uchar_t* __restrict__ X8) {
    __shared__ float tile[32][33];
    const int blk = blockIdx.x;
    if (blk < HBLK) {
        const int stride = HBLK * 256;
        for (int i = blk * 256 + threadIdx.x; i < E; i += stride)
            atomicAdd(&deg[dst[i]], 1);
    } else if (blk < HBLK + 64) {
        const int m = (blk - HBLK) >> 4;
        const int b = (blk - HBLK) & 15;
        const float* W = (m == 0) ? Wa : (m == 1) ? Wb : (m == 2) ? Wc : Wd;
        ushort_t* WT = (m == 0) ? Oa : (m == 1) ? Ob : (m == 2) ? Oc : Od;
        const int by = (b >> 2) * 32;
        const int bx = (b & 3) * 32;
        const int tx = threadIdx.x & 31, ty = threadIdx.x >> 5;
        for (int i = 0; i < 32; i += 8)
            tile[ty + i][tx] = W[(by + ty + i) * F + bx + tx];
        __syncthreads();
        for (int i = 0; i < 32; i += 8)
            WT[(bx + ty + i) * F + by + tx] = f2b(tile[tx][ty + i]);
    } else {
        const int base = (blk - HBLK - 64) * 512;
#pragma unroll
        for (int k = 0; k < 2; k++) {
            const int i = base + k * 256 + threadIdx.x;
            if (i < N4) {
                float4 v = ((const float4*)X)[i];
                us4 o;
                o.x = f2b(v.x); o.y = f2b(v.y); o.z = f2b(v.z); o.w = f2b(v.w);
                ((us4*)Y)[i] = o;
                ((unsigned*)X8)[i] = pack4_fp8(v.x, v.y, v.z, v.w);
            }
        }
    }
}

// ---------------------------------------------------------------------------
// block_sums: bsum[b] = sum of deg[b*1024 .. b*1024+1023]
// ---------------------------------------------------------------------------
__global__ __launch_bounds__(1024) void block_sums(const int* __restrict__ deg,
                                                   int* __restrict__ bsum) {
    __shared__ int s[1024];
    const int t = threadIdx.x;
    const int gid = blockIdx.x * 1024 + t;
    s[t] = (gid < NN) ? deg[gid] : 0;
    __syncthreads();
    for (int d = 512; d > 0; d >>= 1) {
        if (t < d) s[t] += s[t + d];
        __syncthreads();
    }
    if (t == 0) bsum[blockIdx.x] = s[0];
}

// ---------------------------------------------------------------------------
// scan_write: offs = exclusive scan of deg (block scan + redundant top scan
// of the 98 block sums); also inits gcur = offs and offs[NN] = E.
// ---------------------------------------------------------------------------
__global__ __launch_bounds__(1024) void scan_write(const int* __restrict__ deg,
                                                   const int* __restrict__ bsum,
                                                   int* __restrict__ offs,
                                                   int* __restrict__ gcur, int E) {
    __shared__ int sb[128];
    __shared__ int s[1024];
    const int t = threadIdx.x, b = blockIdx.x;
    if (t < 128) sb[t] = (t < NB2) ? bsum[t] : 0;
    __syncthreads();
    for (int d = 1; d < 128; d <<= 1) {
        const int u = (t >= d && t < 128) ? sb[t - d] : 0;
        __syncthreads();
        if (t < 128) sb[t] += u;
        __syncthreads();
    }
    const int pb = (b == 0) ? 0 : sb[b - 1];
    const int gid = b * 1024 + t;
    const int v = (gid < NN) ? deg[gid] : 0;
    s[t] = v;
    __syncthreads();
    for (int d = 1; d < 1024; d <<= 1) {
        const int u = (t >= d) ? s[t - d] : 0;
        __syncthreads();
        s[t] += u;
        __syncthreads();
    }
    const int off = pb + s[t] - v;  // exclusive
    if (gid < NN) {
        offs[gid] = off;
        gcur[gid] = off;
    }
    if (gid == NN) offs[NN] = E;
}

// ---------------------------------------------------------------------------
// scatter_direct: csr[atomicAdd(&gcur[dst])] = src. Returning atomics over
// 100k cursors (~16 deep each). Replaces pairs-scatter + bucket rank-sort;
// within-list order is nondeterministic (sum-order-only effect, +-ULP bf16).
// ---------------------------------------------------------------------------
__global__ __launch_bounds__(256) void scatter_direct(const int* __restrict__ src,
                                                      const int* __restrict__ dst,
                                                      int* __restrict__ gcur,
                                                      int* __restrict__ csr, int E) {
    const int stride = HBLK * 256;
    for (int i = blockIdx.x * 256 + threadIdx.x; i < E; i += stride) {
        const int d = dst[i];
        const int p = atomicAdd(&gcur[d], 1);
        csr[p] = src[i];
    }
}

// ---------------------------------------------------------------------------
// fused SAGE layer (r9/r10-proven, UNCHANGED — its rows are the A/B for the
// src-sort-removal: predict dur <= +2us, FETCH <= +8MB if sort was marginal).
// ---------------------------------------------------------------------------
template <typename TOUT, int GF8>
__global__ __launch_bounds__(256) void sage_layer(
    const ushort_t* __restrict__ Xg, const uchar_t* __restrict__ X8g,
    const int* __restrict__ offs, const int* __restrict__ csr,
    const ushort_t* __restrict__ WTs, const ushort_t* __restrict__ WTn,
    const float* __restrict__ bias,
    TOUT* __restrict__ out, uchar_t* __restrict__ out8, int relu) {
    __shared__ __align__(16) ushort_t sX[32 * LD];
    __shared__ __align__(16) ushort_t sH[32 * LD];
    const int t = threadIdx.x;
    const int lane = t & 63;
    const int wave = t >> 6;
    const int brow0 = blockIdx.x * 32;

    // Phase 0: stage self rows (bf16)
    {
        const ushort_t* base = Xg + (size_t)brow0 * F;
        for (int i = t; i < 32 * 16; i += 256) {
            int row = i >> 4, ch = i & 15;
            *(short8*)&sX[row * LD + ch * 8] = *(const short8*)&base[row * F + ch * 8];
        }
    }

    // Phase A: neighbor mean -> sH (4 slots x 16 lanes)
    {
        const int slot = lane >> 4;
        const int cl = lane & 15;
        const int c8 = cl * 8;
#pragma unroll
        for (int rr = 0; rr < 2; rr++) {
            const int rloc = wave * 8 + slot * 2 + rr;
            const int row = brow0 + rloc;
            const int e0 = offs[row], e1 = offs[row + 1];
            const int d = e1 - e0;
            float acc[8];
#pragma unroll
            for (int j = 0; j < 8; j++) acc[j] = 0.f;
            if (d > 0) {
                const int e1m1 = e1 - 1;
                if constexpr (GF8) {
                    // fp8 gather: 16-deep, 8 B per lane (row stride = 128 B)
                    const int nb = (d + 15) >> 4;
#pragma unroll 1
                    for (int b = 0; b < nb; b++) {
                        const int e = e0 + b * 16;
#define IDX9(K) const int i##K = csr[min(e + K, e1m1)];
                        IDX9(0) IDX9(1) IDX9(2) IDX9(3) IDX9(4) IDX9(5) IDX9(6) IDX9(7)
                        IDX9(8) IDX9(9) IDX9(10) IDX9(11) IDX9(12) IDX9(13) IDX9(14) IDX9(15)
#undef IDX9
#define LDR9(K) int2v r##K = ld_row8(X8g + (size_t)i##K * F + c8);
                        LDR9(0) LDR9(1) LDR9(2) LDR9(3) LDR9(4) LDR9(5) LDR9(6) LDR9(7)
                        LDR9(8) LDR9(9) LDR9(10) LDR9(11) LDR9(12) LDR9(13) LDR9(14) LDR9(15)
#undef LDR9
                        asm volatile("s_waitcnt vmcnt(0)" ::: "memory");
                        asm volatile("" : "+v"(r0), "+v"(r1), "+v"(r2), "+v"(r3),
                                           "+v"(r4), "+v"(r5), "+v"(r6), "+v"(r7),
                                           "+v"(r8), "+v"(r9), "+v"(r10), "+v"(r11),
                                           "+v"(r12), "+v"(r13), "+v"(r14), "+v"(r15));
                        __builtin_amdgcn_sched_barrier(0);
#define ACC9(K) { float tv[8]; dec4(r##K.x, tv); dec4(r##K.y, tv + 4);            \
                  const float mk = (e + K < e1) ? 1.f : 0.f;                      \
                  _Pragma("unroll")                                               \
                  for (int j = 0; j < 8; j++) acc[j] = fmaf(mk, tv[j], acc[j]); }
                        ACC9(0) ACC9(1) ACC9(2) ACC9(3) ACC9(4) ACC9(5) ACC9(6) ACC9(7)
                        ACC9(8) ACC9(9) ACC9(10) ACC9(11) ACC9(12) ACC9(13) ACC9(14) ACC9(15)
#undef ACC9
                    }
                } else {
                    // bf16 gather: r8-proven 8-deep path
                    const int nb = (d + 7) >> 3;
#pragma unroll 1
                    for (int b = 0; b < nb; b++) {
                        const int e = e0 + b * 8;
                        const int i0 = csr[e];
                        const int i1 = csr[min(e + 1, e1m1)];
                        const int i2 = csr[min(e + 2, e1m1)];
                        const int i3 = csr[min(e + 3, e1m1)];
                        const int i4 = csr[min(e + 4, e1m1)];
                        const int i5 = csr[min(e + 5, e1m1)];
                        const int i6 = csr[min(e + 6, e1m1)];
                        const int i7 = csr[min(e + 7, e1m1)];
                        int4v r0 = ld_row16(Xg + (size_t)i0 * F + c8);
                        int4v r1 = ld_row16(Xg + (size_t)i1 * F + c8);
                        int4v r2 = ld_row16(Xg + (size_t)i2 * F + c8);
                        int4v r3 = ld_row16(Xg + (size_t)i3 * F + c8);
                        int4v r4 = ld_row16(Xg + (size_t)i4 * F + c8);
                        int4v r5 = ld_row16(Xg + (size_t)i5 * F + c8);
                        int4v r6 = ld_row16(Xg + (size_t)i6 * F + c8);
                        int4v r7 = ld_row16(Xg + (size_t)i7 * F + c8);
                        asm volatile("s_waitcnt vmcnt(0)" ::: "memory");
                        asm volatile("" : "+v"(r0), "+v"(r1), "+v"(r2), "+v"(r3),
                                           "+v"(r4), "+v"(r5), "+v"(r6), "+v"(r7));
                        __builtin_amdgcn_sched_barrier(0);
                        const short8 v0 = __builtin_bit_cast(short8, r0);
                        const short8 v1 = __builtin_bit_cast(short8, r1);
                        const short8 v2 = __builtin_bit_cast(short8, r2);
                        const short8 v3 = __builtin_bit_cast(short8, r3);
                        const short8 v4 = __builtin_bit_cast(short8, r4);
                        const short8 v5 = __builtin_bit_cast(short8, r5);
                        const short8 v6 = __builtin_bit_cast(short8, r6);
                        const short8 v7 = __builtin_bit_cast(short8, r7);
                        const float m1 = (e + 1 < e1) ? 1.f : 0.f;
                        const float m2 = (e + 2 < e1) ? 1.f : 0.f;
                        const float m3 = (e + 3 < e1) ? 1.f : 0.f;
                        const float m4 = (e + 4 < e1) ? 1.f : 0.f;
                        const float m5 = (e + 5 < e1) ? 1.f : 0.f;
                        const float m6 = (e + 6 < e1) ? 1.f : 0.f;
                        const float m7 = (e + 7 < e1) ? 1.f : 0.f;
#pragma unroll
                        for (int j = 0; j < 8; j++) {
                            float s01 = b2f((ushort_t)v0[j]) + m1 * b2f((ushort_t)v1[j]);
                            float s23 = m2 * b2f((ushort_t)v2[j]) + m3 * b2f((ushort_t)v3[j]);
                            float s45 = m4 * b2f((ushort_t)v4[j]) + m5 * b2f((ushort_t)v5[j]);
                            float s67 = m6 * b2f((ushort_t)v6[j]) + m7 * b2f((ushort_t)v7[j]);
                            acc[j] += (s01 + s23) + (s45 + s67);
                        }
                    }
                }
            }
            const float inv = (d > 0) ? (1.0f / (float)d) : 0.f;
            short8 o;
#pragma unroll
            for (int j = 0; j < 8; j++) o[j] = (short)f2b(acc[j] * inv);
            *(short8*)&sH[rloc * LD + c8] = o;
        }
    }
    __syncthreads();

    // Phase B: MFMA GEMM (wave strip: 32 rows x 32 cols)
    const int q = lane >> 4, nl = lane & 15;
    const int colbase = wave * 32;
    f32x4 acc00 = (f32x4)0.f, acc01 = (f32x4)0.f, acc10 = (f32x4)0.f, acc11 = (f32x4)0.f;
#pragma unroll
    for (int ks = 0; ks < 4; ks++) {
        const int ko = ks * 32 + q * 8;
        const short8 aS0 = *(const short8*)&sX[nl * LD + ko];
        const short8 aS1 = *(const short8*)&sX[(16 + nl) * LD + ko];
        const short8 aN0 = *(const short8*)&sH[nl * LD + ko];
        const short8 aN1 = *(const short8*)&sH[(16 + nl) * LD + ko];
        const size_t bo0 = (size_t)(colbase + nl) * F + ko;
        const size_t bo1 = (size_t)(colbase + 16 + nl) * F + ko;
        const short8 bS0 = *(const short8*)&WTs[bo0];
        const short8 bS1 = *(const short8*)&WTs[bo1];
        const short8 bN0 = *(const short8*)&WTn[bo0];
        const short8 bN1 = *(const short8*)&WTn[bo1];
        acc00 = __builtin_amdgcn_mfma_f32_16x16x32_bf16(aS0, bS0, acc00, 0, 0, 0);
        acc00 = __builtin_amdgcn_mfma_f32_16x16x32_bf16(aN0, bN0, acc00, 0, 0, 0);
        acc01 = __builtin_amdgcn_mfma_f32_16x16x32_bf16(aS0, bS1, acc01, 0, 0, 0);
        acc01 = __builtin_amdgcn_mfma_f32_16x16x32_bf16(aN0, bN1, acc01, 0, 0, 0);
        acc10 = __builtin_amdgcn_mfma_f32_16x16x32_bf16(aS1, bS0, acc10, 0, 0, 0);
        acc10 = __builtin_amdgcn_mfma_f32_16x16x32_bf16(aN1, bN0, acc10, 0, 0, 0);
        acc11 = __builtin_amdgcn_mfma_f32_16x16x32_bf16(aS1, bS1, acc11, 0, 0, 0);
        acc11 = __builtin_amdgcn_mfma_f32_16x16x32_bf16(aN1, bN1, acc11, 0, 0, 0);
    }

    // Epilogue: C/D layout col=lane&15, row=(lane>>4)*4+reg
    const float b0 = bias[colbase + nl];
    const float b1 = bias[colbase + 16 + nl];
    if constexpr (sizeof(TOUT) == 2) {
        __syncthreads();  // all waves done reading sX in phase B
#pragma unroll
        for (int r = 0; r < 4; r++) {
            const int lr0 = q * 4 + r, lr1 = 16 + q * 4 + r;
            float v00 = acc00[r] + b0, v01 = acc01[r] + b1;
            float v10 = acc10[r] + b0, v11 = acc11[r] + b1;
            if (relu) {
                v00 = fmaxf(v00, 0.f); v01 = fmaxf(v01, 0.f);
                v10 = fmaxf(v10, 0.f); v11 = fmaxf(v11, 0.f);
            }
            sX[lr0 * LD + colbase + nl] = f2b(v00);
            sX[lr0 * LD + colbase + 16 + nl] = f2b(v01);
            sX[lr1 * LD + colbase + nl] = f2b(v10);
            sX[lr1 * LD + colbase + 16 + nl] = f2b(v11);
        }
        __syncthreads();
        TOUT* base = out + (size_t)brow0 * F;
        for (int i = t; i < 32 * 16; i += 256) {
            int row = i >> 4, ch = i & 15;
            const short8 v = *(const short8*)&sX[row * LD + ch * 8];
            *(short8*)&base[row * F + ch * 8] = v;
            if (out8) {  // also emit fp8 gather table for layer 2
                float f[8];
#pragma unroll
                for (int j = 0; j < 8; j++) f[j] = b2f((ushort_t)v[j]);
                int2v p;
                p.x = (int)pack4_fp8(f[0], f[1], f[2], f[3]);
                p.y = (int)pack4_fp8(f[4], f[5], f[6], f[7]);
                *(int2v*)&out8[(size_t)(brow0 + row) * F + ch * 8] = p;
            }
        }
    } else {
#pragma unroll
        for (int r = 0; r < 4; r++) {
            const int orow0 = brow0 + q * 4 + r;
            const int orow1 = brow0 + 16 + q * 4 + r;
            float v00 = acc00[r] + b0, v01 = acc01[r] + b1;
            float v10 = acc10[r] + b0, v11 = acc11[r] + b1;
            if (relu) {
                v00 = fmaxf(v00, 0.f); v01 = fmaxf(v01, 0.f);
                v10 = fmaxf(v10, 0.f); v11 = fmaxf(v11, 0.f);
            }
            out[(size_t)orow0 * F + colbase + nl] = v00;
            out[(size_t)orow0 * F + colbase + 16 + nl] = v01;
            out[(size_t)orow1 * F + colbase + nl] = v10;
            out[(size_t)orow1 * F + colbase + 16 + nl] = v11;
        }
    }
}

// ---------------------------------------------------------------------------
extern "C" void kernel_launch(void* const* d_in, const int* in_sizes, int n_in,
                              void* d_out, int out_size, void* d_ws, size_t ws_size,
                              hipStream_t stream) {
    const float* x = (const float*)d_in[0];
    const int* src = (const int*)d_in[1];
    const int* dst = (const int*)d_in[2];
    const float* W1s = (const float*)d_in[3];
    const float* W1n = (const float*)d_in[4];
    const float* b1 = (const float*)d_in[5];
    const float* W2s = (const float*)d_in[6];
    const float* W2n = (const float*)d_in[7];
    const float* b2 = (const float*)d_in[8];
    float* out = (float*)d_out;

    const int E = in_sizes[1];
    const int N = NN;
    const int E4 = (E + 3) & ~3;

    // ws layout: csr[E4] | h1[N*F] bf16 | WT 4*F*F bf16 | offs[N+1] |
    //            deg[N] | gcur[N] | bsum[128] | h1f8[N*F] (gated)
    int* csr = (int*)d_ws;
    ushort_t* h1 = (ushort_t*)(csr + E4);
    ushort_t* WT1s = h1 + (size_t)N * F;
    ushort_t* WT1n = WT1s + F * F;
    ushort_t* WT2s = WT1n + F * F;
    ushort_t* WT2n = WT2s + F * F;
    int* offs = (int*)(WT2n + F * F);
    int* deg = offs + (N + 1);
    int* gcur = deg + N;
    int* bsum = gcur + N;
    // xb (bf16 x) in d_out[0 .. 25.6MB); x8 (fp8 x) in d_out[25.6 .. 38.4MB).
    // Both dead before layer 2 overwrites d_out.
    ushort_t* xb = (ushort_t*)d_out;
    uchar_t* x8 = (uchar_t*)d_out + (size_t)N * F * 2;
    // h1 fp8 table in ws, runtime-gated on ws_size (fallback: bf16 gather).
    size_t off8 = (size_t)((char*)(bsum + 128) - (char*)d_ws);
    off8 = (off8 + 7) & ~(size_t)7;
    uchar_t* h1f8 = (uchar_t*)d_ws + off8;
    const bool l2f8 = ws_size >= off8 + (size_t)N * F;

    // prep: deg=0 -> hist+WT+cvt -> block sums -> scan (offs,gcur) -> scatter
    hipMemsetAsync(deg, 0, (size_t)N * sizeof(int), stream);
    const int cvt_blocks = (N4 + 511) / 512;
    k1_fused<<<HBLK + 64 + cvt_blocks, 256, 0, stream>>>(
        dst, deg, E, W1s, W1n, W2s, W2n, WT1s, WT1n, WT2s, WT2n, x, xb, x8);
    block_sums<<<NB2, 1024, 0, stream>>>(deg, bsum);
    scan_write<<<NB2, 1024, 0, stream>>>(deg, bsum, offs, gcur, E);
    scatter_direct<<<HBLK, 256, 0, stream>>>(src, dst, gcur, csr, E);

    // layer 1: fp8 gather of x8; bf16 h1 out (+ fp8 h1 table if ws allows)
    sage_layer<ushort_t, 1><<<N / 32, 256, 0, stream>>>(
        xb, x8, offs, csr, WT1s, WT1n, b1, h1, l2f8 ? h1f8 : nullptr, 1);
    // layer 2: fp8 gather of h1f8 if available, else proven bf16 path
    if (l2f8) {
        sage_layer<float, 1><<<N / 32, 256, 0, stream>>>(
            h1, h1f8, offs, csr, WT2s, WT2n, b2, out, nullptr, 0);
    } else {
        sage_layer<float, 0><<<N / 32, 256, 0, stream>>>(
            h1, nullptr, offs, csr, WT2s, WT2n, b2, out, nullptr, 0);
    }
}

// Round 12
// 332.286 us; speedup vs baseline: 1.2463x; 1.2463x over previous
//
#include <hip/hip_runtime.h>

#define F 128
#define NN 100000
#define NBUK 782   // ceil(NN/128), 128 nodes per bucket
#define NBLK 256   // sort chunks
#define LD 136     // padded LDS row stride in bf16 elems (272 B)
#define N4 (NN * F / 4)   // 3.2M float4's in x
#define SORT_CAP 8192     // per-bucket LDS sort capacity (mean 2046, sigma ~45)

typedef __attribute__((ext_vector_type(8))) short short8;   // 8 bf16 = 16 B
typedef __attribute__((ext_vector_type(4))) float f32x4;
typedef __attribute__((ext_vector_type(2))) float f32x2;
typedef __attribute__((ext_vector_type(4))) int int4v;
typedef __attribute__((ext_vector_type(2))) int int2v;
typedef __attribute__((ext_vector_type(4))) unsigned short us4;
typedef unsigned short ushort_t;
typedef unsigned char uchar_t;

// ---------------------------------------------------------------------------
// bf16 helpers (RNE)
// ---------------------------------------------------------------------------
__device__ __forceinline__ ushort_t f2b(float f) {
    union { float f; unsigned u; } x;
    x.f = f;
    unsigned r = x.u + 0x7fffu + ((x.u >> 16) & 1u);
    return (ushort_t)(r >> 16);
}
__device__ __forceinline__ float b2f(ushort_t u) {
    union { unsigned u; float f; } x;
    x.u = ((unsigned)u) << 16;
    return x.f;
}

// ---------------------------------------------------------------------------
// fp8 e4m3fn (OCP) helpers. Prefer HW cvt (gfx950 = OCP-native); manual
// branchless fallback implements the identical OCP encoding.
// ---------------------------------------------------------------------------
__device__ __forceinline__ unsigned f_to_e4m3(float v) {
    union { float f; unsigned b; } x; x.f = v;
    unsigned s = (x.b >> 24) & 0x80u;
    float a = fabsf(v);
    if (!(a < 448.f)) return s | 0x7Eu;                       // saturate
    if (a < 0.015625f) return s | (unsigned)__float2int_rn(a * 512.f);  // subnormal
    unsigned ab = x.b & 0x7FFFFFFFu;
    unsigned r = ab + 0x7FFFFu + ((ab >> 20) & 1u);           // RNE at bit 20
    unsigned e = (r >> 23) - 120u;                            // rebias 127->7
    return s | ((e << 3) | ((r >> 20) & 7u));
}
__device__ __forceinline__ float e4m3_to_f(unsigned u) {
    unsigned s = (u & 0x80u) << 24;
    unsigned e = (u >> 3) & 15u;
    unsigned m = u & 7u;
    union { unsigned b; float f; } x;
    x.b = s | ((e + 120u) << 23) | (m << 20);
    float f = x.f;
    if (e == 0) f = fmaf(f, 2.f, s ? 0.015625f : -0.015625f);  // subnormal fix
    return f;
}
__device__ __forceinline__ unsigned pack4_fp8(float f0, float f1, float f2, float f3) {
#if __has_builtin(__builtin_amdgcn_cvt_pk_fp8_f32)
    int w = 0;
    w = __builtin_amdgcn_cvt_pk_fp8_f32(f0, f1, w, false);
    w = __builtin_amdgcn_cvt_pk_fp8_f32(f2, f3, w, true);
    return (unsigned)w;
#else
    return f_to_e4m3(f0) | (f_to_e4m3(f1) << 8) | (f_to_e4m3(f2) << 16) |
           (f_to_e4m3(f3) << 24);
#endif
}
__device__ __forceinline__ void dec4(int w, float* o) {  // 4 fp8 bytes -> f32
#if __has_builtin(__builtin_amdgcn_cvt_pk_f32_fp8)
    f32x2 a = __builtin_amdgcn_cvt_pk_f32_fp8(w, false);
    f32x2 b = __builtin_amdgcn_cvt_pk_f32_fp8(w, true);
    o[0] = a[0]; o[1] = a[1]; o[2] = b[0]; o[3] = b[1];
#else
    o[0] = e4m3_to_f((unsigned)w & 0xFFu);
    o[1] = e4m3_to_f(((unsigned)w >> 8) & 0xFFu);
    o[2] = e4m3_to_f(((unsigned)w >> 16) & 0xFFu);
    o[3] = e4m3_to_f(((unsigned)w >> 24) & 0xFFu);
#endif
}

// Inline-asm loads: distinct "=v" outputs keep all batch results live ->
// true MLP the compiler cannot serialize (r8-proven pattern). Results must
// not be used until after the vmcnt(0) + register-redefine fence.
__device__ __forceinline__ int4v ld_row16(const ushort_t* p) {
    int4v r;
    asm volatile("global_load_dwordx4 %0, %1, off" : "=v"(r) : "v"(p) : "memory");
    return r;
}
__device__ __forceinline__ int2v ld_row8(const uchar_t* p) {
    int2v r;
    asm volatile("global_load_dwordx2 %0, %1, off" : "=v"(r) : "v"(p) : "memory");
    return r;
}

// ---------------------------------------------------------------------------
// K1 (fused): [0,NBLK): chunk bucket histogram -> H[blk][NBUK]
//             [NBLK,NBLK+64): W -> WT bf16 transpose (4 matrices)
//             [NBLK+64,...): FULL x -> bf16 + fp8 cvt (512 float4/block)
// ---------------------------------------------------------------------------
__global__ __launch_bounds__(256) void k1_fused(
    const int* __restrict__ dst, int* __restrict__ H, int E, int chunk,
    const float* __restrict__ Wa, const float* __restrict__ Wb,
    const float* __restrict__ Wc, const float* __restrict__ Wd,
    ushort_t* __restrict__ Oa, ushort_t* __restrict__ Ob,
    ushort_t* __restrict__ Oc, ushort_t* __restrict__ Od,
    const float* __restrict__ X, ushort_t* __restrict__ Y,
    uchar_t* __restrict__ X8) {
    __shared__ union {
        int h[NBUK];
        float tile[32][33];
    } u;
    const int blk = blockIdx.x;
    if (blk < NBLK) {
        for (int i = threadIdx.x; i < NBUK; i += 256) u.h[i] = 0;
        __syncthreads();
        const int s0 = blk * chunk, s1 = min(E, s0 + chunk);
        for (int i = s0 + threadIdx.x; i < s1; i += 256)
            atomicAdd(&u.h[dst[i] >> 7], 1);
        __syncthreads();
        for (int i = threadIdx.x; i < NBUK; i += 256)
            H[blk * NBUK + i] = u.h[i];
    } else if (blk < NBLK + 64) {
        const int m = (blk - NBLK) >> 4;
        const int b = (blk - NBLK) & 15;
        const float* W = (m == 0) ? Wa : (m == 1) ? Wb : (m == 2) ? Wc : Wd;
        ushort_t* WT = (m == 0) ? Oa : (m == 1) ? Ob : (m == 2) ? Oc : Od;
        const int by = (b >> 2) * 32;
        const int bx = (b & 3) * 32;
        const int tx = threadIdx.x & 31, ty = threadIdx.x >> 5;
        for (int i = 0; i < 32; i += 8)
            u.tile[ty + i][tx] = W[(by + ty + i) * F + bx + tx];
        __syncthreads();
        for (int i = 0; i < 32; i += 8)
            WT[(bx + ty + i) * F + by + tx] = f2b(u.tile[tx][ty + i]);
    } else {
        const int base = (blk - NBLK - 64) * 512;
#pragma unroll
        for (int k = 0; k < 2; k++) {
            const int i = base + k * 256 + threadIdx.x;
            if (i < N4) {
                float4 v = ((const float4*)X)[i];
                us4 o;
                o.x = f2b(v.x); o.y = f2b(v.y); o.z = f2b(v.z); o.w = f2b(v.w);
                ((us4*)Y)[i] = o;
                ((unsigned*)X8)[i] = pack4_fp8(v.x, v.y, v.z, v.w);
            }
        }
    }
}

// ---------------------------------------------------------------------------
// scan_cols: block k = bucket k; parallel LDS scan of H[:,k] over NBLK chunks.
// ---------------------------------------------------------------------------
__global__ __launch_bounds__(256) void scan_cols(int* __restrict__ H,
                                                 int* __restrict__ Htot) {
    __shared__ int s[NBLK];
    const int k = blockIdx.x;
    const int t = threadIdx.x;
    const int v = H[t * NBUK + k];
    s[t] = v;
    __syncthreads();
    for (int d = 1; d < NBLK; d <<= 1) {
        const int u = (t >= d) ? s[t - d] : 0;
        __syncthreads();
        s[t] += u;
        __syncthreads();
    }
    H[t * NBUK + k] = s[t] - v;  // exclusive
    if (t == NBLK - 1) Htot[k] = s[t];
}

// ---------------------------------------------------------------------------
// scatter2: each block computes boffs = excl-scan(Htot) itself (782 ints,
// blocked 4/thread + 256-wide scan); block 0 writes boffs for bucket_sort.
// Then the proven LDS-cursor scatter of packed (dstlo<<20 | src) into
// 8KB L2-resident bucket regions (r11 lesson: this L2-locality is what
// avoids the 16x sector write amplification of direct random scatter).
// ---------------------------------------------------------------------------
__global__ __launch_bounds__(256) void scatter2(const int* __restrict__ src,
                                                const int* __restrict__ dst,
                                                const int* __restrict__ H,
                                                const int* __restrict__ Htot,
                                                int* __restrict__ boffs,
                                                unsigned* __restrict__ pairs,
                                                int E, int chunk) {
    __shared__ int cur[NBUK];
    __shared__ int part[256];
    const int b = blockIdx.x;
    const int t = threadIdx.x;
    int v0 = 0, v1 = 0, v2 = 0, v3 = 0;
    {
        const int base = t * 4;
        if (base + 0 < NBUK) v0 = Htot[base + 0];
        if (base + 1 < NBUK) v1 = Htot[base + 1];
        if (base + 2 < NBUK) v2 = Htot[base + 2];
        if (base + 3 < NBUK) v3 = Htot[base + 3];
    }
    const int own = v0 + v1 + v2 + v3;
    part[t] = own;
    __syncthreads();
    for (int d = 1; d < 256; d <<= 1) {
        const int u = (t >= d) ? part[t - d] : 0;
        __syncthreads();
        part[t] += u;
        __syncthreads();
    }
    {
        int run = part[t] - own;
        const int base = t * 4;
        if (base + 0 < NBUK) { cur[base + 0] = run + H[b * NBUK + base + 0]; if (b == 0) boffs[base + 0] = run; run += v0; }
        if (base + 1 < NBUK) { cur[base + 1] = run + H[b * NBUK + base + 1]; if (b == 0) boffs[base + 1] = run; run += v1; }
        if (base + 2 < NBUK) { cur[base + 2] = run + H[b * NBUK + base + 2]; if (b == 0) boffs[base + 2] = run; run += v2; }
        if (base + 3 < NBUK) { cur[base + 3] = run + H[b * NBUK + base + 3]; if (b == 0) boffs[base + 3] = run; run += v3; }
    }
    if (b == 0 && t == 0) boffs[NBUK] = E;
    __syncthreads();
    const int s0 = b * chunk, s1 = min(E, s0 + chunk);
    for (int i = s0 + t; i < s1; i += 256) {
        const int d = dst[i];
        const int p = atomicAdd(&cur[d >> 7], 1);
        pairs[p] = ((unsigned)(d & 127) << 20) | (unsigned)src[i];
    }
}

// ---------------------------------------------------------------------------
// per-bucket counting sort with parallel rank sort (keeps per-dst src-sorted
// lists; edge-parallel, no serial tail; csr writes land in the block's own
// L2-resident region).
// ---------------------------------------------------------------------------
__global__ __launch_bounds__(256) void bucket_sort(const unsigned* __restrict__ pairs,
                                                   const int* __restrict__ boffs,
                                                   int* __restrict__ offs,
                                                   int* __restrict__ csr) {
    __shared__ int cnt[128], loffs[128], lcur[128];
    __shared__ unsigned sbuf[SORT_CAP];
    const int b = blockIdx.x, t = threadIdx.x;
    const int e0 = boffs[b], e1 = boffs[b + 1];
    const int n = e1 - e0;
    const int node0 = b << 7;
    const int nnode = min(128, NN - node0);
    if (t < 128) cnt[t] = 0;
    __syncthreads();
    for (int i = e0 + t; i < e1; i += 256) atomicAdd(&cnt[pairs[i] >> 20], 1);
    __syncthreads();
    if (t < 128) loffs[t] = cnt[t];
    __syncthreads();
    for (int d = 1; d < 128; d <<= 1) {
        int u = (t >= d && t < 128) ? loffs[t - d] : 0;
        __syncthreads();
        if (t < 128) loffs[t] += u;
        __syncthreads();
    }
    if (t < 128) {
        const int ex = loffs[t] - cnt[t];  // exclusive prefix (bucket-relative)
        lcur[t] = ex;
        if (t < nnode) offs[node0 + t] = e0 + ex;
    }
    if (b == NBUK - 1 && t == 0) offs[NN] = e1;
    __syncthreads();

    if (n <= SORT_CAP) {
        for (int i = e0 + t; i < e1; i += 256) {
            const unsigned v = pairs[i];
            const int p = atomicAdd(&lcur[v >> 20], 1);
            sbuf[p] = v;
        }
        __syncthreads();
        for (int i = t; i < n; i += 256) {
            const unsigned v = sbuf[i];
            const int d = v >> 20;
            const int hi = loffs[d];
            const int lo = hi - cnt[d];
            int r = lo;
            for (int j = lo; j < hi; ++j) {
                const unsigned w = sbuf[j];
                r += (w < v) || (w == v && j < i);
            }
            csr[e0 + r] = (int)(v & 0xFFFFFu);
        }
    } else {
        for (int i = e0 + t; i < e1; i += 256) {
            const unsigned v = pairs[i];
            const int p = atomicAdd(&lcur[v >> 20], 1);
            csr[e0 + p] = (int)(v & 0xFFFFFu);
        }
    }
}

// ---------------------------------------------------------------------------
// fused SAGE layer (r9/r10-proven, unchanged). GF8=1: fp8 gather, 16-deep
// asm MLP. At its fabric pattern ceiling (~2.2 TB/s line traffic; r3/r8/r9
// structural invariance).
// ---------------------------------------------------------------------------
template <typename TOUT, int GF8>
__global__ __launch_bounds__(256) void sage_layer(
    const ushort_t* __restrict__ Xg, const uchar_t* __restrict__ X8g,
    const int* __restrict__ offs, const int* __restrict__ csr,
    const ushort_t* __restrict__ WTs, const ushort_t* __restrict__ WTn,
    const float* __restrict__ bias,
    TOUT* __restrict__ out, uchar_t* __restrict__ out8, int relu) {
    __shared__ __align__(16) ushort_t sX[32 * LD];
    __shared__ __align__(16) ushort_t sH[32 * LD];
    const int t = threadIdx.x;
    const int lane = t & 63;
    const int wave = t >> 6;
    const int brow0 = blockIdx.x * 32;

    // Phase 0: stage self rows (bf16)
    {
        const ushort_t* base = Xg + (size_t)brow0 * F;
        for (int i = t; i < 32 * 16; i += 256) {
            int row = i >> 4, ch = i & 15;
            *(short8*)&sX[row * LD + ch * 8] = *(const short8*)&base[row * F + ch * 8];
        }
    }

    // Phase A: neighbor mean -> sH (4 slots x 16 lanes)
    {
        const int slot = lane >> 4;
        const int cl = lane & 15;
        const int c8 = cl * 8;
#pragma unroll
        for (int rr = 0; rr < 2; rr++) {
            const int rloc = wave * 8 + slot * 2 + rr;
            const int row = brow0 + rloc;
            const int e0 = offs[row], e1 = offs[row + 1];
            const int d = e1 - e0;
            float acc[8];
#pragma unroll
            for (int j = 0; j < 8; j++) acc[j] = 0.f;
            if (d > 0) {
                const int e1m1 = e1 - 1;
                if constexpr (GF8) {
                    // fp8 gather: 16-deep, 8 B per lane (row stride = 128 B)
                    const int nb = (d + 15) >> 4;
#pragma unroll 1
                    for (int b = 0; b < nb; b++) {
                        const int e = e0 + b * 16;
#define IDX9(K) const int i##K = csr[min(e + K, e1m1)];
                        IDX9(0) IDX9(1) IDX9(2) IDX9(3) IDX9(4) IDX9(5) IDX9(6) IDX9(7)
                        IDX9(8) IDX9(9) IDX9(10) IDX9(11) IDX9(12) IDX9(13) IDX9(14) IDX9(15)
#undef IDX9
#define LDR9(K) int2v r##K = ld_row8(X8g + (size_t)i##K * F + c8);
                        LDR9(0) LDR9(1) LDR9(2) LDR9(3) LDR9(4) LDR9(5) LDR9(6) LDR9(7)
                        LDR9(8) LDR9(9) LDR9(10) LDR9(11) LDR9(12) LDR9(13) LDR9(14) LDR9(15)
#undef LDR9
                        asm volatile("s_waitcnt vmcnt(0)" ::: "memory");
                        asm volatile("" : "+v"(r0), "+v"(r1), "+v"(r2), "+v"(r3),
                                           "+v"(r4), "+v"(r5), "+v"(r6), "+v"(r7),
                                           "+v"(r8), "+v"(r9), "+v"(r10), "+v"(r11),
                                           "+v"(r12), "+v"(r13), "+v"(r14), "+v"(r15));
                        __builtin_amdgcn_sched_barrier(0);
#define ACC9(K) { float tv[8]; dec4(r##K.x, tv); dec4(r##K.y, tv + 4);            \
                  const float mk = (e + K < e1) ? 1.f : 0.f;                      \
                  _Pragma("unroll")                                               \
                  for (int j = 0; j < 8; j++) acc[j] = fmaf(mk, tv[j], acc[j]); }
                        ACC9(0) ACC9(1) ACC9(2) ACC9(3) ACC9(4) ACC9(5) ACC9(6) ACC9(7)
                        ACC9(8) ACC9(9) ACC9(10) ACC9(11) ACC9(12) ACC9(13) ACC9(14) ACC9(15)
#undef ACC9
                    }
                } else {
                    // bf16 gather: r8-proven 8-deep path
                    const int nb = (d + 7) >> 3;
#pragma unroll 1
                    for (int b = 0; b < nb; b++) {
                        const int e = e0 + b * 8;
                        const int i0 = csr[e];
                        const int i1 = csr[min(e + 1, e1m1)];
                        const int i2 = csr[min(e + 2, e1m1)];
                        const int i3 = csr[min(e + 3, e1m1)];
                        const int i4 = csr[min(e + 4, e1m1)];
                        const int i5 = csr[min(e + 5, e1m1)];
                        const int i6 = csr[min(e + 6, e1m1)];
                        const int i7 = csr[min(e + 7, e1m1)];
                        int4v r0 = ld_row16(Xg + (size_t)i0 * F + c8);
                        int4v r1 = ld_row16(Xg + (size_t)i1 * F + c8);
                        int4v r2 = ld_row16(Xg + (size_t)i2 * F + c8);
                        int4v r3 = ld_row16(Xg + (size_t)i3 * F + c8);
                        int4v r4 = ld_row16(Xg + (size_t)i4 * F + c8);
                        int4v r5 = ld_row16(Xg + (size_t)i5 * F + c8);
                        int4v r6 = ld_row16(Xg + (size_t)i6 * F + c8);
                        int4v r7 = ld_row16(Xg + (size_t)i7 * F + c8);
                        asm volatile("s_waitcnt vmcnt(0)" ::: "memory");
                        asm volatile("" : "+v"(r0), "+v"(r1), "+v"(r2), "+v"(r3),
                                           "+v"(r4), "+v"(r5), "+v"(r6), "+v"(r7));
                        __builtin_amdgcn_sched_barrier(0);
                        const short8 v0 = __builtin_bit_cast(short8, r0);
                        const short8 v1 = __builtin_bit_cast(short8, r1);
                        const short8 v2 = __builtin_bit_cast(short8, r2);
                        const short8 v3 = __builtin_bit_cast(short8, r3);
                        const short8 v4 = __builtin_bit_cast(short8, r4);
                        const short8 v5 = __builtin_bit_cast(short8, r5);
                        const short8 v6 = __builtin_bit_cast(short8, r6);
                        const short8 v7 = __builtin_bit_cast(short8, r7);
                        const float m1 = (e + 1 < e1) ? 1.f : 0.f;
                        const float m2 = (e + 2 < e1) ? 1.f : 0.f;
                        const float m3 = (e + 3 < e1) ? 1.f : 0.f;
                        const float m4 = (e + 4 < e1) ? 1.f : 0.f;
                        const float m5 = (e + 5 < e1) ? 1.f : 0.f;
                        const float m6 = (e + 6 < e1) ? 1.f : 0.f;
                        const float m7 = (e + 7 < e1) ? 1.f : 0.f;
#pragma unroll
                        for (int j = 0; j < 8; j++) {
                            float s01 = b2f((ushort_t)v0[j]) + m1 * b2f((ushort_t)v1[j]);
                            float s23 = m2 * b2f((ushort_t)v2[j]) + m3 * b2f((ushort_t)v3[j]);
                            float s45 = m4 * b2f((ushort_t)v4[j]) + m5 * b2f((ushort_t)v5[j]);
                            float s67 = m6 * b2f((ushort_t)v6[j]) + m7 * b2f((ushort_t)v7[j]);
                            acc[j] += (s01 + s23) + (s45 + s67);
                        }
                    }
                }
            }
            const float inv = (d > 0) ? (1.0f / (float)d) : 0.f;
            short8 o;
#pragma unroll
            for (int j = 0; j < 8; j++) o[j] = (short)f2b(acc[j] * inv);
            *(short8*)&sH[rloc * LD + c8] = o;
        }
    }
    __syncthreads();

    // Phase B: MFMA GEMM (wave strip: 32 rows x 32 cols)
    const int q = lane >> 4, nl = lane & 15;
    const int colbase = wave * 32;
    f32x4 acc00 = (f32x4)0.f, acc01 = (f32x4)0.f, acc10 = (f32x4)0.f, acc11 = (f32x4)0.f;
#pragma unroll
    for (int ks = 0; ks < 4; ks++) {
        const int ko = ks * 32 + q * 8;
        const short8 aS0 = *(const short8*)&sX[nl * LD + ko];
        const short8 aS1 = *(const short8*)&sX[(16 + nl) * LD + ko];
        const short8 aN0 = *(const short8*)&sH[nl * LD + ko];
        const short8 aN1 = *(const short8*)&sH[(16 + nl) * LD + ko];
        const size_t bo0 = (size_t)(colbase + nl) * F + ko;
        const size_t bo1 = (size_t)(colbase + 16 + nl) * F + ko;
        const short8 bS0 = *(const short8*)&WTs[bo0];
        const short8 bS1 = *(const short8*)&WTs[bo1];
        const short8 bN0 = *(const short8*)&WTn[bo0];
        const short8 bN1 = *(const short8*)&WTn[bo1];
        acc00 = __builtin_amdgcn_mfma_f32_16x16x32_bf16(aS0, bS0, acc00, 0, 0, 0);
        acc00 = __builtin_amdgcn_mfma_f32_16x16x32_bf16(aN0, bN0, acc00, 0, 0, 0);
        acc01 = __builtin_amdgcn_mfma_f32_16x16x32_bf16(aS0, bS1, acc01, 0, 0, 0);
        acc01 = __builtin_amdgcn_mfma_f32_16x16x32_bf16(aN0, bN1, acc01, 0, 0, 0);
        acc10 = __builtin_amdgcn_mfma_f32_16x16x32_bf16(aS1, bS0, acc10, 0, 0, 0);
        acc10 = __builtin_amdgcn_mfma_f32_16x16x32_bf16(aN1, bN0, acc10, 0, 0, 0);
        acc11 = __builtin_amdgcn_mfma_f32_16x16x32_bf16(aS1, bS1, acc11, 0, 0, 0);
        acc11 = __builtin_amdgcn_mfma_f32_16x16x32_bf16(aN1, bN1, acc11, 0, 0, 0);
    }

    // Epilogue: C/D layout col=lane&15, row=(lane>>4)*4+reg
    const float b0 = bias[colbase + nl];
    const float b1 = bias[colbase + 16 + nl];
    if constexpr (sizeof(TOUT) == 2) {
        __syncthreads();  // all waves done reading sX in phase B
#pragma unroll
        for (int r = 0; r < 4; r++) {
            const int lr0 = q * 4 + r, lr1 = 16 + q * 4 + r;
            float v00 = acc00[r] + b0, v01 = acc01[r] + b1;
            float v10 = acc10[r] + b0, v11 = acc11[r] + b1;
            if (relu) {
                v00 = fmaxf(v00, 0.f); v01 = fmaxf(v01, 0.f);
                v10 = fmaxf(v10, 0.f); v11 = fmaxf(v11, 0.f);
            }
            sX[lr0 * LD + colbase + nl] = f2b(v00);
            sX[lr0 * LD + colbase + 16 + nl] = f2b(v01);
            sX[lr1 * LD + colbase + nl] = f2b(v10);
            sX[lr1 * LD + colbase + 16 + nl] = f2b(v11);
        }
        __syncthreads();
        TOUT* base = out + (size_t)brow0 * F;
        for (int i = t; i < 32 * 16; i += 256) {
            int row = i >> 4, ch = i & 15;
            const short8 v = *(const short8*)&sX[row * LD + ch * 8];
            *(short8*)&base[row * F + ch * 8] = v;
            if (out8) {  // also emit fp8 gather table for layer 2
                float f[8];
#pragma unroll
                for (int j = 0; j < 8; j++) f[j] = b2f((ushort_t)v[j]);
                int2v p;
                p.x = (int)pack4_fp8(f[0], f[1], f[2], f[3]);
                p.y = (int)pack4_fp8(f[4], f[5], f[6], f[7]);
                *(int2v*)&out8[(size_t)(brow0 + row) * F + ch * 8] = p;
            }
        }
    } else {
#pragma unroll
        for (int r = 0; r < 4; r++) {
            const int orow0 = brow0 + q * 4 + r;
            const int orow1 = brow0 + 16 + q * 4 + r;
            float v00 = acc00[r] + b0, v01 = acc01[r] + b1;
            float v10 = acc10[r] + b0, v11 = acc11[r] + b1;
            if (relu) {
                v00 = fmaxf(v00, 0.f); v01 = fmaxf(v01, 0.f);
                v10 = fmaxf(v10, 0.f); v11 = fmaxf(v11, 0.f);
            }
            out[(size_t)orow0 * F + colbase + nl] = v00;
            out[(size_t)orow0 * F + colbase + 16 + nl] = v01;
            out[(size_t)orow1 * F + colbase + nl] = v10;
            out[(size_t)orow1 * F + colbase + 16 + nl] = v11;
        }
    }
}

// ---------------------------------------------------------------------------
extern "C" void kernel_launch(void* const* d_in, const int* in_sizes, int n_in,
                              void* d_out, int out_size, void* d_ws, size_t ws_size,
                              hipStream_t stream) {
    const float* x = (const float*)d_in[0];
    const int* src = (const int*)d_in[1];
    const int* dst = (const int*)d_in[2];
    const float* W1s = (const float*)d_in[3];
    const float* W1n = (const float*)d_in[4];
    const float* b1 = (const float*)d_in[5];
    const float* W2s = (const float*)d_in[6];
    const float* W2n = (const float*)d_in[7];
    const float* b2 = (const float*)d_in[8];
    float* out = (float*)d_out;

    const int E = in_sizes[1];
    const int N = NN;
    const int E4 = (E + 3) & ~3;
    const int chunk = (E + NBLK - 1) / NBLK;

    unsigned* pairs = (unsigned*)d_ws;
    int* csr = (int*)(pairs + E4);
    ushort_t* h1 = (ushort_t*)(csr + E4);
    ushort_t* WT1s = h1 + (size_t)N * F;
    ushort_t* WT1n = WT1s + F * F;
    ushort_t* WT2s = WT1n + F * F;
    ushort_t* WT2n = WT2s + F * F;
    int* offs = (int*)(WT2n + F * F);
    int* H = offs + (N + 1);
    int* boffs = H + NBLK * NBUK;
    int* Htot = boffs + (NBUK + 1);
    // xb (bf16 x) in d_out[0 .. 25.6MB); x8 (fp8 x) in d_out[25.6 .. 38.4MB).
    // Both dead before layer 2 overwrites d_out.
    ushort_t* xb = (ushort_t*)d_out;
    uchar_t* x8 = (uchar_t*)d_out + (size_t)N * F * 2;
    // h1 fp8 table in ws, runtime-gated on ws_size (fallback: bf16 gather).
    size_t off8 = (size_t)((char*)(Htot + NBUK) - (char*)d_ws);
    off8 = (off8 + 7) & ~(size_t)7;
    uchar_t* h1f8 = (uchar_t*)d_ws + off8;
    const bool l2f8 = ws_size >= off8 + (size_t)N * F;

    // k1: hist + WT + FULL cvt (512 float4 per block)
    const int cvt_blocks = (N4 + 511) / 512;
    k1_fused<<<NBLK + 64 + cvt_blocks, 256, 0, stream>>>(
        dst, H, E, chunk, W1s, W1n, W2s, W2n, WT1s, WT1n, WT2s, WT2n, x, xb, x8);
    scan_cols<<<NBUK, NBLK, 0, stream>>>(H, Htot);
    // scatter2 self-computes boffs from Htot
    scatter2<<<NBLK, 256, 0, stream>>>(src, dst, H, Htot, boffs, pairs, E, chunk);
    bucket_sort<<<NBUK, 256, 0, stream>>>(pairs, boffs, offs, csr);

    // layer 1: fp8 gather of x8; bf16 h1 out (+ fp8 h1 table if ws allows)
    sage_layer<ushort_t, 1><<<N / 32, 256, 0, stream>>>(
        xb, x8, offs, csr, WT1s, WT1n, b1, h1, l2f8 ? h1f8 : nullptr, 1);
    // layer 2: fp8 gather of h1f8 if available, else proven bf16 path
    if (l2f8) {
        sage_layer<float, 1><<<N / 32, 256, 0, stream>>>(
            h1, h1f8, offs, csr, WT2s, WT2n, b2, out, nullptr, 0);
    } else {
        sage_layer<float, 0><<<N / 32, 256, 0, stream>>>(
            h1, nullptr, offs, csr, WT2s, WT2n, b2, out, nullptr, 0);
    }
}